// Round 8
// baseline (186.684 us; speedup 1.0000x reference)
//
#include <hip/hip_runtime.h>
#include <math.h>

#define Bn 2
#define Cc 256
#define Hh 64
#define Ww 96
#define Nn (Hh*Ww)       // 6144
#define NLEV 5
#define SCH 4            // column chunks per row-tile
#define CPC (Nn/SCH)     // 1536 cols per block
#define ROWT 48          // rows per block tile
#define NITER (CPC/128)  // 12 col-iterations of 128 cols
#define TKEEP 6          // per-thread kept list length
#define KNEG __uint_as_float(0xFF7FFFFFu)   // most-negative finite float

typedef __bf16 bf16x8 __attribute__((ext_vector_type(8)));
typedef float f32x4v __attribute__((ext_vector_type(4)));

// branchless sorted-descending insert of packed key into VA[LEN]
#define KEY_INS(k, VA, LEN) do {                                          \
  float _c = (k);                                                         \
  _Pragma("unroll")                                                       \
  for (int _s = 0; _s < (LEN); ++_s) {                                    \
    float _h = fmaxf(VA[_s], _c);                                         \
    _c = fminf(VA[_s], _c);                                               \
    VA[_s] = _h;                                                          \
  }                                                                       \
} while (0)

// exact (value,index) insert — tiny rescore phases only
#define TOPK_INS(v, ix, VA, IA, LEN) do {                                 \
  if ((v) > VA[(LEN)-1]) {                                                \
    VA[(LEN)-1] = (v); IA[(LEN)-1] = (ix);                                \
    _Pragma("unroll")                                                     \
    for (int _s = (LEN)-1; _s > 0; --_s) {                                \
      if (VA[_s] > VA[_s-1]) {                                            \
        float _t = VA[_s]; VA[_s] = VA[_s-1]; VA[_s-1] = _t;              \
        int   _u = IA[_s]; IA[_s] = IA[_s-1]; IA[_s-1] = _u;              \
      }                                                                   \
    }                                                                     \
  }                                                                       \
} while (0)

__device__ __forceinline__ void gld16(const void* g, void* l) {
  __builtin_amdgcn_global_load_lds(
      (const __attribute__((address_space(1))) void*)g,
      (__attribute__((address_space(3))) void*)l, 16, 0, 0);
}

__device__ inline unsigned short f2bf(float f) {
  __bf16 h = (__bf16)f;
  return __builtin_bit_cast(unsigned short, h);
}

// ---------------------------------------------------------------------------
// Kernel A: [C][N] fp32 -> [N][C] bf16 + [N][C] fp32 (transpose + convert)
// ---------------------------------------------------------------------------
__global__ __launch_bounds__(256) void transpose_convert(
    const float* __restrict__ f1, const float* __restrict__ f2,
    __bf16* __restrict__ t1b, __bf16* __restrict__ t2b,
    float* __restrict__ t1f, float* __restrict__ t2f)
{
  __shared__ float tile[64][65];
  const int tid = threadIdx.x;
  const int bid = blockIdx.x;
  const int map = bid / 768;
  const int rem = bid % 768;
  const int b   = rem / 384;
  const int r2  = rem % 384;
  const int c0  = (r2 / 96) * 64;
  const int n0  = (r2 % 96) * 64;

  const float* src = (map ? f2 : f1) + (size_t)b*Cc*Nn;
  __bf16* dstb = (map ? t2b : t1b) + (size_t)b*Nn*Cc;
  float*  dstf = (map ? t2f : t1f) + (size_t)b*Nn*Cc;

  const int nl = tid & 63;
  const int cb = tid >> 6;
  #pragma unroll
  for (int i = 0; i < 16; ++i) {
    const int c = cb + i*4;
    tile[nl][c] = src[(size_t)(c0 + c)*Nn + n0 + nl];
  }
  __syncthreads();
  #pragma unroll
  for (int j = 0; j < 4; ++j) {
    const int idx = j*256 + tid;
    const int n = idx >> 4, c4 = idx & 15;
    float v0 = tile[n][c4*4+0], v1 = tile[n][c4*4+1];
    float v2 = tile[n][c4*4+2], v3 = tile[n][c4*4+3];
    const size_t obase = (size_t)(n0 + n)*Cc + c0 + c4*4;
    float4 vf = make_float4(v0, v1, v2, v3);
    *(float4*)(dstf + obase) = vf;
    ushort4 ub = make_ushort4(f2bf(v0), f2bf(v1), f2bf(v2), f2bf(v3));
    *(ushort4*)(dstb + obase) = ub;
  }
}

// ---------------------------------------------------------------------------
// Kernel B: bf16 MFMA correlation + packed-key per-thread top-6 prefilter.
// 1024 blocks x 256 thr (4 waves). Tile: 48 f1-rows x 1536 f2-cols, K=256.
// f1 fragments: ALL 24 (3 cg x 8 kc) loaded global->VGPR once (no As tile,
// no block barrier in the whole GEMM). LDS = Bs 2x8KB dbuf only.
// Ladder guarded per 4-candidate group by wave-uniform __any.
// ---------------------------------------------------------------------------
__global__ __launch_bounds__(256, 3) void mfma_prefilter(
    const __bf16* __restrict__ f1t, const __bf16* __restrict__ f2t,
    unsigned* __restrict__ pv)
{
  __shared__ __align__(16) char smem[18688];
  // Bs[q]: q*8192, 128 cols x 64 B (per-wave 2 KB quadrants)
  unsigned* mk = (unsigned*)smem;        // merge keys [48][97] u32 (18.6 KB)

  const int tid  = threadIdx.x;
  const int lane = tid & 63;
  const int wv   = tid >> 6;
  const int bid  = blockIdx.x;
  const int b    = bid / (128*SCH);
  const int r2   = bid % (128*SCH);
  const int row0 = (r2 >> 2) * ROWT;     // 128 row-tiles of 48
  const int sc   = r2 & 3;
  const int col0 = sc * CPC;
  const size_t bN = (size_t)b * Nn;

  // ---- load ALL f1 fragments direct global->VGPR (wave-independent)
  bf16x8 bfrH[3][8];
  #pragma unroll
  for (int kc = 0; kc < 8; ++kc)
    #pragma unroll
    for (int cg = 0; cg < 3; ++cg) {
      const int rw = cg*16 + (lane & 15);
      bfrH[cg][kc] = *(const bf16x8*)(
          f1t + ((bN + row0 + rw) << 8) + kc*32 + ((lane >> 4) << 3));
    }

  // ---- per-lane source offsets for B staging (wave quadrant: 32 cols/iter)
  size_t offB[2];
  #pragma unroll
  for (int i = 0; i < 2; ++i) {
    const int cl = wv*32 + i*16 + (lane >> 2);       // col within 128-col iter
    const int g2 = (lane & 3) ^ ((cl >> 1) & 3);     // pre-swizzled source granule
    offB[i] = ((bN + col0 + cl) << 8) + (g2 << 3);
  }
  #define STAGE_B(q, elemoff) do {                                        \
    _Pragma("unroll")                                                     \
    for (int _i = 0; _i < 2; ++_i)                                        \
      gld16(f2t + offB[_i] + (elemoff),                                   \
            smem + (q)*8192 + wv*2048 + _i*1024);                         \
  } while (0)

  STAGE_B(0, 0);
  // drains the 24 frag loads (oldest); B0 (2 newest) stays in flight
  asm volatile("s_waitcnt vmcnt(2)" ::: "memory");
  __builtin_amdgcn_sched_barrier(0);

  float va[3][TKEEP];
  #pragma unroll
  for (int cg = 0; cg < 3; ++cg)
    #pragma unroll
    for (int j = 0; j < TKEEP; ++j) va[cg][j] = KNEG;

  for (int iter = 0; iter < NITER; ++iter) {
    f32x4v acc[2][3];
    #pragma unroll
    for (int rg = 0; rg < 2; ++rg)
      #pragma unroll
      for (int cg = 0; cg < 3; ++cg)
        acc[rg][cg] = (f32x4v){0.f, 0.f, 0.f, 0.f};

    #pragma unroll
    for (int kc = 0; kc < 8; ++kc) {
      if (kc < 7) {
        STAGE_B((kc+1)&1, (size_t)iter*32768 + (kc+1)*32);
        asm volatile("s_waitcnt vmcnt(2)" ::: "memory");
      } else if (iter < NITER-1) {
        STAGE_B(0, (size_t)(iter+1)*32768);
        asm volatile("s_waitcnt vmcnt(2)" ::: "memory");
      } else {
        asm volatile("s_waitcnt vmcnt(0)" ::: "memory");
      }
      __builtin_amdgcn_sched_barrier(0);

      bf16x8 af[2];
      const int q = kc & 1;
      #pragma unroll
      for (int rg = 0; rg < 2; ++rg) {               // f2 cols (A-operand)
        const int cl = wv*32 + rg*16 + (lane & 15);
        const int gsw = (lane >> 4) ^ ((cl >> 1) & 3);
        af[rg] = *(const bf16x8*)(smem + q*8192 + cl*64 + gsw*16);
      }
      __builtin_amdgcn_s_setprio(1);
      #pragma unroll
      for (int rg = 0; rg < 2; ++rg)
        #pragma unroll
        for (int cg = 0; cg < 3; ++cg)
          acc[rg][cg] = __builtin_amdgcn_mfma_f32_16x16x32_bf16(
              af[rg], bfrH[cg][kc], acc[rg][cg], 0, 0, 0);
      __builtin_amdgcn_s_setprio(0);
    }

    // packed-key top-6 update, guarded per 4-candidate group (wave-uniform)
    const int colB = col0 + iter*128 + wv*32 + ((lane >> 4) << 2);
    #pragma unroll
    for (int cg = 0; cg < 3; ++cg)
      #pragma unroll
      for (int rg = 0; rg < 2; ++rg) {
        float k4[4];
        #pragma unroll
        for (int j = 0; j < 4; ++j) {
          const unsigned u =
              (__float_as_uint(acc[rg][cg][j]) & 0xFFFFE000u) |
              (unsigned)(colB + rg*16 + j);
          k4[j] = __uint_as_float(u);
        }
        const float gmax = fmaxf(fmaxf(k4[0], k4[1]), fmaxf(k4[2], k4[3]));
        if (__any(gmax > va[cg][TKEEP-1])) {
          #pragma unroll
          for (int j = 0; j < 4; ++j)
            KEY_INS(k4[j], va[cg], TKEEP);
        }
      }
  }

  // ---- final merge: 16 thread-lists per row (96 keys) -> top-8 per row ----
  __syncthreads();
  const int slot = wv*4 + (lane >> 4);
  #pragma unroll
  for (int cg = 0; cg < 3; ++cg) {
    const int row = cg*16 + (lane & 15);
    #pragma unroll
    for (int j = 0; j < TKEEP; ++j)
      mk[row*97 + slot*TKEEP + j] = __float_as_uint(va[cg][j]);
  }
  __syncthreads();
  if (tid < ROWT) {
    float tv[8];
    #pragma unroll
    for (int j = 0; j < 8; ++j) tv[j] = KNEG;
    for (int e = 0; e < 16*TKEEP; ++e)
      KEY_INS(__uint_as_float(mk[tid*97 + e]), tv, 8);
    const size_t base = (bN + row0 + tid)*32 + sc*8;
    #pragma unroll
    for (int j = 0; j < 8; ++j) pv[base + j] = __float_as_uint(tv[j]);
  }
}

// ---------------------------------------------------------------------------
// Kernel C: 32 keys -> approx top-16 -> exact fp32 rescore -> exact top-8.
// 1536 blocks x 256 thr, 8 n each; f1 staged once in LDS; gather loops
// fully unrolled for load ILP (latency-bound on t2f).
// ---------------------------------------------------------------------------
__global__ __launch_bounds__(256) void rescore_select(
    const unsigned* __restrict__ pv,
    const float* __restrict__ t1f, const float* __restrict__ t2f,
    float* __restrict__ fv, int* __restrict__ fi)
{
  __shared__ float f1s[8][256];    // 8 KB
  __shared__ int   cidx[8][16];
  __shared__ float cex[8][16];

  const int tid = threadIdx.x;
  const int bid = blockIdx.x;
  const int b   = bid / 768;
  const int n0  = (bid % 768) * 8;
  const size_t bn0 = (size_t)b*Nn + n0;

  // stage f1 rows: 8 x 1 KB
  #pragma unroll
  for (int k = 0; k < 2; ++k) {
    const int idx = k*256 + tid;
    const int r = idx >> 6, p = idx & 63;
    *(float4*)(&f1s[r][p*4]) = *(const float4*)(t1f + (bn0 + r)*256 + p*4);
  }

  // phase 1: one thread per n: key-ladder top-16 of 32
  if (tid < 8) {
    float va[16];
    #pragma unroll
    for (int j = 0; j < 16; ++j) va[j] = KNEG;
    const size_t base = (bn0 + tid)*32;
    for (int e = 0; e < 32; ++e)
      KEY_INS(__uint_as_float(pv[base + e]), va, 16);
    #pragma unroll
    for (int j = 0; j < 16; ++j)
      cidx[tid][j] = (int)(__float_as_uint(va[j]) & 0x1FFFu);
  }
  __syncthreads();

  // phase 2: exact fp32 rescore: wave handles 2 n; 8 lanes per candidate
  {
    const int lane = tid & 63;
    const int cg = lane >> 3, li = lane & 7;
    #pragma unroll
    for (int nn = 0; nn < 2; ++nn) {
      const int nl = (tid >> 6)*2 + nn;
      #pragma unroll
      for (int p = 0; p < 2; ++p) {
        const int cand = p*8 + cg;
        const int m = cidx[nl][cand];
        const float4* p2 = (const float4*)(t2f + ((size_t)b*Nn + m)*256);
        float sum = 0.f;
        #pragma unroll
        for (int j = 0; j < 8; ++j) {
          const int fi4 = j*8 + li;
          float4 a = *(const float4*)(&f1s[nl][fi4*4]);
          float4 c = p2[fi4];
          sum += a.x*c.x + a.y*c.y + a.z*c.z + a.w*c.w;
        }
        sum += __shfl_xor(sum, 1);
        sum += __shfl_xor(sum, 2);
        sum += __shfl_xor(sum, 4);
        if (li == 0) cex[nl][cand] = sum;
      }
    }
  }
  __syncthreads();

  // phase 3: exact top-8 of 16, write final
  if (tid < 8) {
    float va[8]; int ia[8];
    #pragma unroll
    for (int j = 0; j < 8; ++j) { va[j] = -INFINITY; ia[j] = 0; }
    #pragma unroll
    for (int e = 0; e < 16; ++e)
      TOPK_INS(cex[tid][e], cidx[tid][e], va, ia, 8);
    const size_t base = (bn0 + tid)*8;
    #pragma unroll
    for (int j = 0; j < 8; ++j) { fv[base+j] = va[j]; fi[base+j] = ia[j]; }
  }
}

// ---------------------------------------------------------------------------
// Kernel D: displacement -> 5-level bilinear scatter
// ---------------------------------------------------------------------------
__global__ __launch_bounds__(128) void pyramid_kernel(
    const float* __restrict__ fv, const int* __restrict__ fi,
    const float* __restrict__ flow, float* __restrict__ out)
{
  __shared__ float accs[128*81];
  const int tid = threadIdx.x;
  const int g   = blockIdx.x*128 + tid;   // b*N + n
  const int lvl = blockIdx.y;
  const int b   = g / Nn;
  const int n   = g % Nn;

  float tvv[8]; int ti[8];
  #pragma unroll
  for (int k = 0; k < 8; ++k) { tvv[k] = fv[(size_t)g*8 + k]; ti[k] = fi[(size_t)g*8 + k]; }

  const int y = n / Ww, x = n % Ww;
  const float fly = flow[((size_t)b*2 + 1)*Nn + n];
  const float flx = flow[((size_t)b*2 + 0)*Nn + n];
  const float scale = 1.0f / (float)(1 << lvl);

  float* lacc = &accs[tid*81];
  #pragma unroll
  for (int c2 = 0; c2 < 81; ++c2) lacc[c2] = 0.f;

  #pragma unroll
  for (int k = 0; k < 8; ++k) {
    const int m  = ti[k];
    const int ym = m / Ww, xm = m % Ww;
    const float val = tvv[k] * 0.0625f;
    const float cy = ((float)(ym - y) - fly) * scale;
    const float cx = ((float)(xm - x) - flx) * scale;
    const float fy0 = floorf(cy), fx0 = floorf(cx);
    const float ry = cy - fy0, rx = cx - fx0;
    const int iy = (int)fy0, ix = (int)fx0;
    if (iy   >= -4 && iy   <= 4 && ix   >= -4 && ix   <= 4)
      lacc[(iy+4)*9 + (ix+4)]     += (1.f-ry)*(1.f-rx)*val;
    if (iy   >= -4 && iy   <= 4 && ix+1 >= -4 && ix+1 <= 4)
      lacc[(iy+4)*9 + (ix+1+4)]   += (1.f-ry)*rx*val;
    if (iy+1 >= -4 && iy+1 <= 4 && ix   >= -4 && ix   <= 4)
      lacc[(iy+1+4)*9 + (ix+4)]   += ry*(1.f-rx)*val;
    if (iy+1 >= -4 && iy+1 <= 4 && ix+1 >= -4 && ix+1 <= 4)
      lacc[(iy+1+4)*9 + (ix+1+4)] += ry*rx*val;
  }

  const size_t obase = ((size_t)b*(NLEV*81) + lvl*81) * Nn + n;
  #pragma unroll
  for (int c2 = 0; c2 < 81; ++c2)
    out[obase + (size_t)c2*Nn] = lacc[c2];
}

// ---------------------------------------------------------------------------
extern "C" void kernel_launch(void* const* d_in, const int* in_sizes, int n_in,
                              void* d_out, int out_size, void* d_ws, size_t ws_size,
                              hipStream_t stream) {
  const float* fmap1 = (const float*)d_in[0];
  const float* fmap2 = (const float*)d_in[1];
  const float* flow  = (const float*)d_in[2];
  float* out = (float*)d_out;

  char* w = (char*)d_ws;
  const size_t szBf  = (size_t)Bn*Nn*Cc*sizeof(unsigned short); // 6.29 MB
  const size_t szF   = (size_t)Bn*Nn*Cc*sizeof(float);          // 12.58 MB
  const size_t szPv  = (size_t)Bn*Nn*32*sizeof(unsigned);       // 1.57 MB
  const size_t szFv  = (size_t)Bn*Nn*8*sizeof(float);           // 0.39 MB

  __bf16*   t1b = (__bf16*)(w);
  __bf16*   t2b = (__bf16*)(w + szBf);
  float*    t1f = (float*)(w + 2*szBf);
  float*    t2f = (float*)(w + 2*szBf + szF);
  unsigned* pv  = (unsigned*)(w + 2*szBf + 2*szF);
  float*    fv  = (float*)(w + 2*szBf + 2*szF + szPv);
  int*      fi  = (int*)  (w + 2*szBf + 2*szF + szPv + szFv);

  transpose_convert<<<dim3(1536), dim3(256), 0, stream>>>(fmap1, fmap2, t1b, t2b, t1f, t2f);
  mfma_prefilter  <<<dim3(Bn*128*SCH), dim3(256), 0, stream>>>(t1b, t2b, pv);
  rescore_select  <<<dim3(1536), dim3(256), 0, stream>>>(pv, t1f, t2f, fv, fi);
  pyramid_kernel  <<<dim3(96, NLEV), dim3(128), 0, stream>>>(fv, fi, flow, out);
}